// Round 1
// baseline (254.527 us; speedup 1.0000x reference)
//
#include <hip/hip_runtime.h>
#include <math.h>
#include <float.h>

#define D 256
#define K 1024
#define NROWS 32768
#define ROWS 16          // rows per block (was 32): acc 128->64 VGPR, 4 waves/SIMD
#define MARGIN 1.0f      // z-margin for np-replica near-tie refinement (fp16 fast-z)
#define MAXCAND 12

#define LOSS_OFF 8388608
#define IDX_OFF  8388609

typedef _Float16 h8 __attribute__((ext_vector_type(8)));
typedef float    v4f __attribute__((ext_vector_type(4)));

// ---- numpy pairwise sum replica for sum(a*a) over 128 contiguous floats ----
__device__ __forceinline__ float np_sq_block128(const float* a) {
    float r0 = __fmul_rn(a[0], a[0]);
    float r1 = __fmul_rn(a[1], a[1]);
    float r2 = __fmul_rn(a[2], a[2]);
    float r3 = __fmul_rn(a[3], a[3]);
    float r4 = __fmul_rn(a[4], a[4]);
    float r5 = __fmul_rn(a[5], a[5]);
    float r6 = __fmul_rn(a[6], a[6]);
    float r7 = __fmul_rn(a[7], a[7]);
    for (int i = 8; i < 128; i += 8) {
        r0 = __fadd_rn(r0, __fmul_rn(a[i + 0], a[i + 0]));
        r1 = __fadd_rn(r1, __fmul_rn(a[i + 1], a[i + 1]));
        r2 = __fadd_rn(r2, __fmul_rn(a[i + 2], a[i + 2]));
        r3 = __fadd_rn(r3, __fmul_rn(a[i + 3], a[i + 3]));
        r4 = __fadd_rn(r4, __fmul_rn(a[i + 4], a[i + 4]));
        r5 = __fadd_rn(r5, __fmul_rn(a[i + 5], a[i + 5]));
        r6 = __fadd_rn(r6, __fmul_rn(a[i + 6], a[i + 6]));
        r7 = __fadd_rn(r7, __fmul_rn(a[i + 7], a[i + 7]));
    }
    float tA = __fadd_rn(__fadd_rn(r0, r1), __fadd_rn(r2, r3));
    float tB = __fadd_rn(__fadd_rn(r4, r5), __fadd_rn(r6, r7));
    return __fadd_rn(tA, tB);
}

// ---- fused prep: fragment convert + b2 (numpy-exact) + ws zeroing ----------
// cfrag[(s*64 + T)*64 + qd*16 + ln] = f16x8 of code (T*16+ln), dims s*32+qd*8..+7
__global__ void vq_prep(const float* __restrict__ cb, float* __restrict__ b2,
                        h8* __restrict__ cfrag, float* __restrict__ avg_acc,
                        float* __restrict__ scal) {
    int tid = blockIdx.x * 256 + threadIdx.x;      // 0..32767
    // fragment-ordered fp16 convert (coalesced 16B writes)
    {
        int ln = tid & 15;
        int qd = (tid >> 4) & 3;
        int T  = (tid >> 6) & 63;
        int s  = tid >> 12;
        int k  = T * 16 + ln;
        const float* c = cb + (size_t)k * D + s * 32 + qd * 8;
        float4 v0 = *(const float4*)c;
        float4 v1 = *(const float4*)(c + 4);
        h8 f;
        f[0] = (_Float16)v0.x; f[1] = (_Float16)v0.y;
        f[2] = (_Float16)v0.z; f[3] = (_Float16)v0.w;
        f[4] = (_Float16)v1.x; f[5] = (_Float16)v1.y;
        f[6] = (_Float16)v1.z; f[7] = (_Float16)v1.w;
        cfrag[tid] = f;
    }
    // numpy-exact codebook norms
    if (tid < K) {
        const float* c = cb + (size_t)tid * D;
        b2[tid] = __fadd_rn(np_sq_block128(c), np_sq_block128(c + 128));
    }
    // zero the accumulators (kernel-order guarantees visibility before vq_mfma)
    if (tid >= 1024 && tid < 2048) avg_acc[tid - 1024] = 0.f;
    if (tid >= 2048 && tid < 2050) scal[tid - 2048] = 0.f;
}

// ---- fused MFMA distance GEMM + argmin + softmax stats + outputs -----------
// Block: 256 thr = 4 waves = 4 code-quarters; each wave: 16 rows x 256 codes.
// B fragments read DIRECTLY from L2-resident cfrag (no LDS stage, no vmcnt
// drain): each wave previously read back exactly the tiles it DMA'd itself,
// so the LDS round-trip bought nothing and its 64 KB capped occupancy at 2
// blocks/CU. Now: ~6 KB LDS, 64-reg accumulator -> 4 blocks/CU, 16 waves/CU.
__global__ __launch_bounds__(256, 4)
void vq_mfma(const float* __restrict__ x, const float* __restrict__ cb,
             const h8* __restrict__ cfrag, const float* __restrict__ b2,
             float* __restrict__ avg_acc, float* __restrict__ scal,
             float* __restrict__ out)
{
    __shared__ float mred[4][ROWS];
    __shared__ int   kred[4][ROWS];
    __shared__ float sred[4][ROWS];
    __shared__ float tred[4][ROWS];
    __shared__ int   bkl[ROWS];
    __shared__ int   candn[ROWS];
    __shared__ int   candk[ROWS][MAXCAND];
    __shared__ __align__(16) float xbw[4][256];    // per-wave slow-path row stage

    const int t   = threadIdx.x;
    const int w   = t >> 6;        // wave = code-quarter q (0..3)
    const int q   = w;
    const int l64 = t & 63;
    const int qd  = l64 >> 4;      // k-chunk (A/B) / row-subgroup (C)
    const int ln  = l64 & 15;      // m (A) / n (B) / col (C)
    const int r0  = blockIdx.x * ROWS;

    if (t < ROWS) candn[t] = 0;

    v4f acc[16];                   // [code-tile]; rows 4*qd..4*qd+3 per lane
    #pragma unroll
    for (int tt = 0; tt < 16; ++tt) acc[tt] = (v4f)0.f;

    const float* ab = x + (size_t)(r0 + ln) * D + qd * 8;

    // A prefetch for step 0
    float4 pa0 = *(const float4*)(ab);
    float4 pa1 = *(const float4*)(ab + 4);

    for (int s = 0; s < 8; ++s) {
        h8 af;
        af[0] = (_Float16)pa0.x; af[1] = (_Float16)pa0.y;
        af[2] = (_Float16)pa0.z; af[3] = (_Float16)pa0.w;
        af[4] = (_Float16)pa1.x; af[5] = (_Float16)pa1.y;
        af[6] = (_Float16)pa1.z; af[7] = (_Float16)pa1.w;
        if (s < 7) {                               // A prefetch for s+1
            pa0 = *(const float4*)(ab + (s + 1) * 32);
            pa1 = *(const float4*)(ab + (s + 1) * 32 + 4);
        }
        const h8* bq = cfrag + ((size_t)(s * 64 + 16 * q)) * 64 + l64;
        #pragma unroll
        for (int tt = 0; tt < 16; ++tt) {
            h8 bf = bq[(size_t)tt * 64];           // coalesced 16B, L2-hit
            acc[tt] = __builtin_amdgcn_mfma_f32_16x16x32_f16(af, bf, acc[tt], 0, 0, 0);
        }
    }

    // ---- z = 200*dot - 100*||c||^2 ----
    float b2c[16];
    #pragma unroll
    for (int tt = 0; tt < 16; ++tt) b2c[tt] = b2[256 * q + 16 * tt + ln];
    #pragma unroll
    for (int tt = 0; tt < 16; ++tt)
        #pragma unroll
        for (int r = 0; r < 4; ++r)
            acc[tt][r] = 200.f * acc[tt][r] - 100.f * b2c[tt];

    // ---- per-row local max over this wave's 16 cols ----
    float m[4]; int bk[4];
    #pragma unroll
    for (int r = 0; r < 4; ++r) { m[r] = -INFINITY; bk[r] = K; }
    #pragma unroll
    for (int tt = 0; tt < 16; ++tt)
        #pragma unroll
        for (int r = 0; r < 4; ++r) {
            float z = acc[tt][r];
            int code = 256 * q + 16 * tt + ln;
            if (z > m[r]) { m[r] = z; bk[r] = code; }
        }
    #pragma unroll
    for (int off = 1; off < 16; off <<= 1)
        #pragma unroll
        for (int r = 0; r < 4; ++r) {
            float om = __shfl_xor(m[r], off);
            int   ok = __shfl_xor(bk[r], off);
            if (om > m[r] || (om == m[r] && ok < bk[r])) { m[r] = om; bk[r] = ok; }
        }
    if (ln == 0)
        #pragma unroll
        for (int r = 0; r < 4; ++r) {
            int rl = 4 * qd + r;
            mred[q][rl] = m[r]; kred[q][rl] = bk[r];
        }
    __syncthreads();

    // ---- combine quarters (codes ascend with quarter -> '>' keeps low idx) --
    float mf[4]; int kf[4];
    #pragma unroll
    for (int r = 0; r < 4; ++r) {
        int rl = 4 * qd + r;
        mf[r] = mred[0][rl]; kf[r] = kred[0][rl];
        #pragma unroll
        for (int qq = 1; qq < 4; ++qq) {
            float mm = mred[qq][rl];
            if (mm > mf[r]) { mf[r] = mm; kf[r] = kred[qq][rl]; }
        }
    }

    // ---- S,T with global max; candidate append; stash e-values ----
    float S[4] = {0, 0, 0, 0}, T[4] = {0, 0, 0, 0};
    #pragma unroll
    for (int tt = 0; tt < 16; ++tt)
        #pragma unroll
        for (int r = 0; r < 4; ++r) {
            float z  = acc[tt][r];
            float zz = z - mf[r];
            float e  = __expf(zz);
            if (z > mf[r] - MARGIN) {
                int rl = 4 * qd + r;
                int slot = atomicAdd(&candn[rl], 1);
                if (slot < MAXCAND) candk[rl][slot] = 256 * q + 16 * tt + ln;
            }
            S[r] += e; T[r] += zz * e;
            acc[tt][r] = e;
        }
    #pragma unroll
    for (int off = 1; off < 16; off <<= 1)
        #pragma unroll
        for (int r = 0; r < 4; ++r) {
            S[r] += __shfl_xor(S[r], off);
            T[r] += __shfl_xor(T[r], off);
        }
    if (ln == 0)
        #pragma unroll
        for (int r = 0; r < 4; ++r) {
            int rl = 4 * qd + r;
            sred[q][rl] = S[r]; tred[q][rl] = T[r];
        }
    __syncthreads();

    float iS[4];
    float hsum = 0.f;
    #pragma unroll
    for (int r = 0; r < 4; ++r) {
        int rl = 4 * qd + r;
        float Sf = sred[0][rl] + sred[1][rl] + sred[2][rl] + sred[3][rl];
        float Tf = tred[0][rl] + tred[1][rl] + tred[2][rl] + tred[3][rl];
        iS[r] = 1.f / Sf;
        if (q == 0 && ln == 0) {
            bkl[rl] = kf[r];
            hsum += Tf * iS[r] - __logf(Sf);
        }
    }
    if (q == 0 && ln == 0) atomicAdd(&scal[1], hsum);

    // ---- sparse avg_probs emission ----
    #pragma unroll
    for (int tt = 0; tt < 16; ++tt)
        #pragma unroll
        for (int r = 0; r < 4; ++r) {
            float p = acc[tt][r] * iS[r];
            if (p > 1e-12f)
                atomicAdd(&avg_acc[256 * q + 16 * tt + ln], p);
        }
    __syncthreads();

    // ---- near-tie slow path: numpy fp32-pipeline replica -------------------
    // Parallelized across waves: wave w refines rows 4w..4w+3 (was: wave 0
    // serially over all rows while 3 waves idled at the barrier).
    for (int j = 0; j < 4; ++j) {
        int rl = 4 * w + j;
        int tc = candn[rl];
        if (tc < 2) continue;
        if (tc > MAXCAND) tc = MAXCAND;
        const float* xr = x + (size_t)(r0 + rl) * D;
        *(float4*)&xbw[w][l64 * 4] = *(const float4*)(xr + l64 * 4);
        float a2f = __fadd_rn(np_sq_block128((const float*)xbw[w]),
                              np_sq_block128((const float*)xbw[w] + 128));
        float bestd = FLT_MAX; int bestk = K;
        for (int c = 0; c < tc; ++c) {
            int k = candk[rl][c];
            double sdot = 0.0;
            #pragma unroll
            for (int dd = 0; dd < 4; ++dd)
                sdot += (double)cb[(size_t)k * D + l64 * 4 + dd] *
                        (double)xbw[w][l64 * 4 + dd];
            #pragma unroll
            for (int off = 32; off > 0; off >>= 1)
                sdot += __shfl_xor(sdot, off);
            float abf = (float)sdot;
            float dnp = __fsub_rn(__fadd_rn(a2f, b2[k]), __fmul_rn(2.0f, abf));
            if (dnp < bestd || (dnp == bestd && k < bestk)) {
                bestd = dnp; bestk = k;
            }
        }
        if (l64 == 0) bkl[rl] = bestk;
    }
    __syncthreads();

    // ---- outputs: wave w -> rows 4w..4w+3 ----
    float wmse = 0.f;
    #pragma unroll
    for (int rr = 0; rr < 4; ++rr) {
        int rl  = 4 * w + rr;
        int row = r0 + rl;
        int bk2 = bkl[rl];
        float4 xv = *(const float4*)(x  + (size_t)row * D + l64 * 4);
        float4 qv = *(const float4*)(cb + (size_t)bk2 * D + l64 * 4);
        float dx = qv.x - xv.x, dy = qv.y - xv.y, dz = qv.z - xv.z, dw = qv.w - xv.w;
        float4 st;
        st.x = xv.x + dx; st.y = xv.y + dy; st.z = xv.z + dz; st.w = xv.w + dw;
        *(float4*)(out + (size_t)row * D + l64 * 4) = st;
        if (l64 == 0) out[IDX_OFF + row] = (float)bk2;
        wmse += dx * dx + dy * dy + dz * dz + dw * dw;
    }
    #pragma unroll
    for (int off = 32; off > 0; off >>= 1)
        wmse += __shfl_xor(wmse, off);
    if (l64 == 0) atomicAdd(&scal[0], wmse);
}

// ---- finalize loss ----------------------------------------------------------
__global__ __launch_bounds__(1024)
void vq_fin(const float* __restrict__ avg_acc, const float* __restrict__ scal,
            float* __restrict__ out)
{
    __shared__ float sred[16];
    int t = threadIdx.x;
    float ap = avg_acc[t] * (1.f / 32768.f);
    float v = ap * logf(ap + 1e-5f);
    #pragma unroll
    for (int off = 32; off > 0; off >>= 1) v += __shfl_xor(v, off);
    if ((t & 63) == 0) sred[t >> 6] = v;
    __syncthreads();
    if (t == 0) {
        float s = 0.f;
        for (int w = 0; w < 16; ++w) s += sred[w];
        float avg_entropy = -s;
        float sampleH = -scal[1] * (1.f / 32768.f);
        float mse = scal[0] * (1.f / 8388608.f);
        float loss = 1.25f * mse + 0.1f * (sampleH - avg_entropy);
        out[LOSS_OFF] = loss;
    }
}

extern "C" void kernel_launch(void* const* d_in, const int* in_sizes, int n_in,
                              void* d_out, int out_size, void* d_ws, size_t ws_size,
                              hipStream_t stream)
{
    const float* x  = (const float*)d_in[0];
    const float* cb = (const float*)d_in[1];
    float* out = (float*)d_out;
    float* ws  = (float*)d_ws;
    float* b2      = ws;                                   // [1024]
    float* avg_acc = ws + K;                               // [1024]
    float* scal    = ws + 2 * K;                           // [2]
    h8*    cfrag   = (h8*)((char*)d_ws + 16384);           // [4096*64] frags (512 KB)

    vq_prep<<<128, 256, 0, stream>>>(cb, b2, cfrag, avg_acc, scal);
    vq_mfma<<<NROWS / ROWS, 256, 0, stream>>>(x, cb, cfrag, b2, avg_acc, scal, out);
    vq_fin<<<1, 1024, 0, stream>>>(avg_acc, scal, out);
}